// Round 1
// baseline (727.770 us; speedup 1.0000x reference)
//
#include <hip/hip_runtime.h>
#include <stdint.h>
#include <math.h>

#define N_B 4
#define T_S 4096
#define D_M 1024
#define H_M 1536
#define NT  (N_B * T_S)   // 16384
#define G2  (2 * H_M)     // 3072
#define LCH 64            // timesteps per chunk
#define NCH 64            // chunks (LCH*NCH == T_S)

typedef __attribute__((ext_vector_type(8))) short short8;
typedef __attribute__((ext_vector_type(4))) float floatx4;

__device__ __forceinline__ unsigned short f2bf(float f) {
  unsigned u = __float_as_uint(f);
  u += 0x7fff + ((u >> 16) & 1);            // RNE
  return (unsigned short)(u >> 16);
}
__device__ __forceinline__ float bf2f(unsigned short u) {
  return __uint_as_float(((unsigned)u) << 16);
}
__device__ __forceinline__ float bf_lo(unsigned p) { return __uint_as_float(p << 16); }
__device__ __forceinline__ float bf_hi(unsigned p) { return __uint_as_float(p & 0xffff0000u); }
__device__ __forceinline__ unsigned bf_pack(float lo, float hi) {
  return ((unsigned)f2bf(lo)) | (((unsigned)f2bf(hi)) << 16);
}
__device__ __forceinline__ float sigmoidf_(float x) { return 1.f / (1.f + __expf(-x)); }
__device__ __forceinline__ float softplusf_(float x) {
  return (x > 20.f) ? x : log1pf(__expf(x));
}
__device__ __forceinline__ float geluf_(float x) {
  return 0.5f * x * (1.f + erff(x * 0.70710678118654752f));
}

// ---------------- zero-fill fallback (diagnostic if ws_size too small) ----------------
__global__ void zero_out(float* __restrict__ out, int n) {
  int i = blockIdx.x * 256 + threadIdx.x;
  if (i < n) out[i] = 0.f;
}

// ---------------- fused f32 -> bf16 conversion of x, Win, Wg (one launch) ----------------
#define N4_X   (NT * D_M / 4)          // 4,194,304
#define N4_WIN (G2 * D_M / 4)          //   786,432
#define N4_WG  (G2 * H_M / 4)          // 1,179,648
__global__ void cvt3_bf16(const float* __restrict__ x, unsigned short* __restrict__ x16,
                          const float* __restrict__ win, unsigned short* __restrict__ win16,
                          const float* __restrict__ wg, unsigned short* __restrict__ wg16) {
  int i = blockIdx.x * 256 + threadIdx.x;
  const float* in; unsigned short* out;
  if (i < N4_X)                { in = x;   out = x16; }
  else if (i < N4_X + N4_WIN)  { in = win; out = win16; i -= N4_X; }
  else if (i < N4_X + N4_WIN + N4_WG) { in = wg; out = wg16; i -= N4_X + N4_WIN; }
  else return;
  float4 v = ((const float4*)in)[i];
  ushort4 o;
  o.x = f2bf(v.x); o.y = f2bf(v.y); o.z = f2bf(v.z); o.w = f2bf(v.w);
  ((ushort4*)out)[i] = o;
}

__global__ void cvt_bf16(const float* __restrict__ in, unsigned short* __restrict__ out, int n4) {
  int i = blockIdx.x * 256 + threadIdx.x;
  if (i >= n4) return;
  float4 v = ((const float4*)in)[i];
  ushort4 o;
  o.x = f2bf(v.x); o.y = f2bf(v.y); o.z = f2bf(v.z); o.w = f2bf(v.w);
  ((ushort4*)out)[i] = o;
}

// ---------------- bf16 MFMA GEMM, 256x256 tile, 8-phase counted-vmcnt schedule ----------
// C[m,n] = sum_k A[m,k]*B[n,k] (+bias[n]).  512 threads = 8 waves (2 Mx4 N), BK=64.
// LDS 128 KiB: [buf 2][op A/B][khalf 2][256 rows x 32 k] bf16, double-buffered.
// Per K-tile: 4 phases (ksub, mh), 16 MFMA each; B-frags reused across mh phases.
// Staging: during tile t, phases 1..4 stage A.kh0/B.kh0/A.kh1/B.kh1 of tile t+1 into
// buf[d^1] (dead for all of tile t -> no mid-tile slot hazard). Counted waits:
//   vmcnt(4) @ phase-2 end (A.kh1(t),B.kh1(t) landed; leaves A.kh0(t+1),B.kh0(t+1) in flight)
//   vmcnt(4) @ phase-4 end (A.kh0(t+1),B.kh0(t+1) landed; leaves kh1(t+1) in flight)
// Never drains to 0 in the main loop (last tile: vmcnt(0) once).  Raw s_barrier (no
// __syncthreads drain), s_setprio(1) around each MFMA cluster (T5).
// Bank balance: within a 32-k half row (4 slots of 8 bf16), physical slot = logical ^ (row&3);
// applied on the GLOBAL source address (global_load_lds dest stays linear, rule #21) and
// on the ds_read address (slot = kq ^ (fr&3)) -> balanced 8 lanes per 4-bank group = 0 extra cycles.
// XCD swizzle: nwg divisible by 8 for all three GEMMs -> simple bijective chunk map.
#define TM 256
#define TN 256

__device__ __forceinline__ void stage16(const unsigned short* g, unsigned short* l) {
  __builtin_amdgcn_global_load_lds((__attribute__((address_space(1))) void*)g,
                                   (__attribute__((address_space(3))) void*)l, 16, 0, 0);
}

template<bool BIAS, bool OUT_BF16, bool SPLIT>
__global__ __launch_bounds__(512, 2)
void gemm_bt8(const unsigned short* __restrict__ A,
              const unsigned short* __restrict__ B,
              void* __restrict__ Cv, void* __restrict__ Cv2,
              const float* __restrict__ bias,
              int N, int K) {
  // [buf][op][khalf][256*32 elems] = 128 KiB
  __shared__ __align__(16) unsigned short lds[2][2][2][8192];
  const int tid  = threadIdx.x;
  const int lane = tid & 63;
  const int wave = tid >> 6;
  const int wr = wave >> 2;                  // 0..1  (M half of tile)
  const int wc = wave & 3;                   // 0..3  (N quarter of tile)

  // bijective XCD-aware block swizzle (nwg % 8 == 0 for all shapes used)
  const int gx  = gridDim.x;
  const int nwg = gx * gridDim.y;
  const int bid = blockIdx.y * gx + blockIdx.x;
  const int cpx = nwg >> 3;
  const int swz = (bid & 7) * cpx + (bid >> 3);
  const int bm = (swz / gx) * TM;
  const int bn = (swz % gx) * TN;

  floatx4 acc[8][4];
#pragma unroll
  for (int i = 0; i < 8; i++)
#pragma unroll
    for (int j = 0; j < 4; j++)
      acc[i][j] = (floatx4){0.f, 0.f, 0.f, 0.f};

  // ---- staging addresses: one half-tile (op, kh) = 1024 16B chunks; thread does c=tid, c+512
  // chunk c -> row r=c>>2, phys slot sl=c&3 holds logical k-group kg = sl ^ (r&3)
  const int r1  = tid >> 2;                  // 0..127
  const int sl  = tid & 3;
  const int kg  = (sl ^ (r1 & 3)) * 8;       // (r1+128)&3 == r1&3, same for chunk 2
  const unsigned short* Ag1 = A + (size_t)(bm + r1)       * K + kg;
  const unsigned short* Ag2 = A + (size_t)(bm + r1 + 128) * K + kg;
  const unsigned short* Bg1 = B + (size_t)(bn + r1)       * K + kg;
  const unsigned short* Bg2 = B + (size_t)(bn + r1 + 128) * K + kg;
  const int ld1 = tid * 8;                   // elem offset in region
  const int ld2 = ld1 + 4096;

#define STAGE_A(buf, kh, k0) do { \
    stage16(Ag1 + (k0) + (kh) * 32, &lds[buf][0][kh][ld1]); \
    stage16(Ag2 + (k0) + (kh) * 32, &lds[buf][0][kh][ld2]); } while (0)
#define STAGE_B(buf, kh, k0) do { \
    stage16(Bg1 + (k0) + (kh) * 32, &lds[buf][1][kh][ld1]); \
    stage16(Bg2 + (k0) + (kh) * 32, &lds[buf][1][kh][ld2]); } while (0)

  // ---- fragment read bases: lane (fr, kq); phys slot = kq ^ (fr&3)
  const int fr = lane & 15;
  const int kq = lane >> 4;
  const int so = (kq ^ (fr & 3)) * 8;
  const int abase = (wr * 128 + fr) * 32 + so;   // + mh*2048 + i*512
  const int bbase = (wc * 64 + fr) * 32 + so;    // + j*512

  const int nt = K >> 6;

  // prologue: stage tile 0; wait kh0 halves (leave kh1 in flight = steady-state invariant)
  STAGE_A(0, 0, 0); STAGE_B(0, 0, 0); STAGE_A(0, 1, 0); STAGE_B(0, 1, 0);
  asm volatile("s_waitcnt vmcnt(4)" ::: "memory");
  __builtin_amdgcn_s_barrier();

  for (int t = 0; t < nt; ++t) {
    const int d = t & 1;
    const int kn = (t + 1) << 6;
    const bool st = (t + 1 < nt);
    const unsigned short* As0 = &lds[d][0][0][0];
    const unsigned short* Bs0 = &lds[d][1][0][0];
    const unsigned short* As1 = &lds[d][0][1][0];
    const unsigned short* Bs1 = &lds[d][1][1][0];
    short8 af[4], bfr[4];

    // ---- phase 1: ksub0, mh0 ----
#pragma unroll
    for (int i = 0; i < 4; ++i) af[i]  = *(const short8*)(As0 + abase + i * 512);
#pragma unroll
    for (int j = 0; j < 4; ++j) bfr[j] = *(const short8*)(Bs0 + bbase + j * 512);
    if (st) STAGE_A(d ^ 1, 0, kn);
    __builtin_amdgcn_s_barrier();
    __builtin_amdgcn_s_setprio(1);
#pragma unroll
    for (int i = 0; i < 4; ++i)
#pragma unroll
      for (int j = 0; j < 4; ++j)
        acc[i][j] = __builtin_amdgcn_mfma_f32_16x16x32_bf16(af[i], bfr[j], acc[i][j], 0, 0, 0);
    __builtin_amdgcn_s_setprio(0);
    __builtin_amdgcn_s_barrier();

    // ---- phase 2: ksub0, mh1 (reuse bfr) ----
#pragma unroll
    for (int i = 0; i < 4; ++i) af[i] = *(const short8*)(As0 + abase + 2048 + i * 512);
    if (st) STAGE_B(d ^ 1, 0, kn);
    __builtin_amdgcn_s_barrier();
    __builtin_amdgcn_s_setprio(1);
#pragma unroll
    for (int i = 0; i < 4; ++i)
#pragma unroll
      for (int j = 0; j < 4; ++j)
        acc[4 + i][j] = __builtin_amdgcn_mfma_f32_16x16x32_bf16(af[i], bfr[j], acc[4 + i][j], 0, 0, 0);
    __builtin_amdgcn_s_setprio(0);
    if (t == nt - 1) { asm volatile("s_waitcnt vmcnt(0)" ::: "memory"); }
    else             { asm volatile("s_waitcnt vmcnt(4)" ::: "memory"); }
    __builtin_amdgcn_s_barrier();

    // ---- phase 3: ksub1, mh0 ----
#pragma unroll
    for (int i = 0; i < 4; ++i) af[i]  = *(const short8*)(As1 + abase + i * 512);
#pragma unroll
    for (int j = 0; j < 4; ++j) bfr[j] = *(const short8*)(Bs1 + bbase + j * 512);
    if (st) STAGE_A(d ^ 1, 1, kn);
    __builtin_amdgcn_s_barrier();
    __builtin_amdgcn_s_setprio(1);
#pragma unroll
    for (int i = 0; i < 4; ++i)
#pragma unroll
      for (int j = 0; j < 4; ++j)
        acc[i][j] = __builtin_amdgcn_mfma_f32_16x16x32_bf16(af[i], bfr[j], acc[i][j], 0, 0, 0);
    __builtin_amdgcn_s_setprio(0);
    __builtin_amdgcn_s_barrier();

    // ---- phase 4: ksub1, mh1 (reuse bfr) ----
#pragma unroll
    for (int i = 0; i < 4; ++i) af[i] = *(const short8*)(As1 + abase + 2048 + i * 512);
    if (st) STAGE_B(d ^ 1, 1, kn);
    __builtin_amdgcn_s_barrier();
    __builtin_amdgcn_s_setprio(1);
#pragma unroll
    for (int i = 0; i < 4; ++i)
#pragma unroll
      for (int j = 0; j < 4; ++j)
        acc[4 + i][j] = __builtin_amdgcn_mfma_f32_16x16x32_bf16(af[i], bfr[j], acc[4 + i][j], 0, 0, 0);
    __builtin_amdgcn_s_setprio(0);
    if (st) { asm volatile("s_waitcnt vmcnt(4)" ::: "memory"); }
    __builtin_amdgcn_s_barrier();
  }
#undef STAGE_A
#undef STAGE_B

  // C/D layout (m89-verified): col = lane&15, row = (lane>>4)*4 + reg
  const int half  = SPLIT ? (N >> 1) : N;
  const bool hi   = SPLIT && (bn >= half);
  void* Cb        = hi ? Cv2 : Cv;
  const int coff  = hi ? half : 0;
  const int cn = lane & 15;
  const int rb = (lane >> 4) * 4;
#pragma unroll
  for (int j = 0; j < 4; ++j) {
    const int col = bn + wc * 64 + j * 16 + cn;
    const float bv = BIAS ? bias[col] : 0.f;
#pragma unroll
    for (int i = 0; i < 8; ++i) {
      const int row0 = bm + wr * 128 + i * 16 + rb;
#pragma unroll
      for (int r = 0; r < 4; ++r) {
        float v = acc[i][j][r] + bv;
        size_t idx = (size_t)(row0 + r) * half + (col - coff);
        if (OUT_BF16) ((unsigned short*)Cb)[idx] = f2bf(v);
        else          ((float*)Cb)[idx] = v;
      }
    }
  }
}

// ---------------- depthwise causal conv (K=4) + bias, 2 channels/thread ----------------
__global__ void conv_dw(const unsigned int* __restrict__ xbpre2, const float* __restrict__ cw,
                        const float* __restrict__ cb, unsigned int* __restrict__ xbc2) {
  int i0 = blockIdx.x * 256 + threadIdx.x;       // pair index, 0..H_M/2-1
  int t = blockIdx.y;
  size_t nt = (size_t)blockIdx.z * T_S + t;
  const int h = 2 * i0;
  const float4 wa = ((const float4*)cw)[h];      // taps for channel h
  const float4 wb = ((const float4*)cw)[h + 1];  // taps for channel h+1
  const float2 cb2 = ((const float2*)cb)[i0];
  size_t base = nt * (H_M / 2) + i0;
  unsigned p0 = xbpre2[base];
  float aa = cb2.x + wa.w * bf_lo(p0);
  float ab = cb2.y + wb.w * bf_hi(p0);
  if (t >= 1) { unsigned p = xbpre2[base - H_M / 2];
    aa += wa.z * bf_lo(p); ab += wb.z * bf_hi(p); }
  if (t >= 2) { unsigned p = xbpre2[base - 2 * (size_t)(H_M / 2)];
    aa += wa.y * bf_lo(p); ab += wb.y * bf_hi(p); }
  if (t >= 3) { unsigned p = xbpre2[base - 3 * (size_t)(H_M / 2)];
    aa += wa.x * bf_lo(p); ab += wb.x * bf_hi(p); }
  xbc2[base] = bf_pack(aa, ab);
}

// ---------------- chunked linear scan (2 channels/thread) ----------------
__global__ void scan_A(const unsigned int* __restrict__ fg2, const unsigned int* __restrict__ xbc2,
                       const float* __restrict__ fb,
                       float2* __restrict__ cA2, float2* __restrict__ cS2) {
  int i0 = blockIdx.x * 256 + threadIdx.x;       // pair index
  int ch = blockIdx.y;
  int n = blockIdx.z;
  const float2 fb2 = ((const float2*)fb)[i0];
  const float c8a = 8.f * softplusf_(fb2.x);
  const float c8b = 8.f * softplusf_(fb2.y);
  float apa = 1.f, sa = 0.f, apb = 1.f, sb = 0.f;
  size_t r = (size_t)n * T_S + (size_t)ch * LCH;
  for (int i = 0; i < LCH; i++, r++) {
    unsigned pf = fg2[r * (G2 / 2) + i0];
    unsigned pi = fg2[r * (G2 / 2) + H_M / 2 + i0];
    unsigned px = xbc2[r * (H_M / 2) + i0];
    float alpha_a = __expf(-c8a * sigmoidf_(bf_lo(pf)));
    float alpha_b = __expf(-c8b * sigmoidf_(bf_hi(pf)));
    float beta_a = sqrtf(1.f - alpha_a * alpha_a + 1e-6f);
    float beta_b = sqrtf(1.f - alpha_b * alpha_b + 1e-6f);
    sa = alpha_a * sa + beta_a * sigmoidf_(bf_lo(pi)) * bf_lo(px);
    sb = alpha_b * sb + beta_b * sigmoidf_(bf_hi(pi)) * bf_hi(px);
    apa *= alpha_a;
    apb *= alpha_b;
  }
  size_t o = ((size_t)n * NCH + ch) * (H_M / 2) + i0;
  cA2[o] = make_float2(apa, apb);
  cS2[o] = make_float2(sa, sb);
}

// phase C: per-block prescan of chunk summaries (L2-hot) computes the carry-in,
// then replay with fused gelu(gate)*h written IN-PLACE over the gate buffer.
__global__ void scan_C(const unsigned int* __restrict__ fg2, const unsigned int* __restrict__ xbc2,
                       const float* __restrict__ fb,
                       const float2* __restrict__ cA2, const float2* __restrict__ cS2,
                       unsigned int* gateh2) {
  int i0 = blockIdx.x * 256 + threadIdx.x;
  int ch = blockIdx.y;
  int n = blockIdx.z;
  const float2 fb2 = ((const float2*)fb)[i0];
  const float c8a = 8.f * softplusf_(fb2.x);
  const float c8b = 8.f * softplusf_(fb2.y);
  float sa = 0.f, sb = 0.f;
  for (int c = 0; c < ch; c++) {
    size_t o = ((size_t)n * NCH + c) * (H_M / 2) + i0;
    float2 a = cA2[o], s = cS2[o];
    sa = a.x * sa + s.x;
    sb = a.y * sb + s.y;
  }
  size_t r = (size_t)n * T_S + (size_t)ch * LCH;
  for (int i = 0; i < LCH; i++, r++) {
    unsigned pf = fg2[r * (G2 / 2) + i0];
    unsigned pi = fg2[r * (G2 / 2) + H_M / 2 + i0];
    unsigned px = xbc2[r * (H_M / 2) + i0];
    float alpha_a = __expf(-c8a * sigmoidf_(bf_lo(pf)));
    float alpha_b = __expf(-c8b * sigmoidf_(bf_hi(pf)));
    float beta_a = sqrtf(1.f - alpha_a * alpha_a + 1e-6f);
    float beta_b = sqrtf(1.f - alpha_b * alpha_b + 1e-6f);
    sa = alpha_a * sa + beta_a * sigmoidf_(bf_lo(pi)) * bf_lo(px);
    sb = alpha_b * sb + beta_b * sigmoidf_(bf_hi(pi)) * bf_hi(px);
    unsigned pg = gateh2[r * (H_M / 2) + i0];
    gateh2[r * (H_M / 2) + i0] = bf_pack(geluf_(bf_lo(pg)) * sa, geluf_(bf_hi(pg)) * sb);
  }
}

// ---------------- launcher ----------------
// Workspace layout (S = NT*H_M*2 = 50,331,648 B; peak = 4S + 9.4 MB ≈ 210.8 MB):
//   [0,S)    gate16 (GEMM1 out, lo half) -> scan_C in-place -> gh16 (GEMM3 A)
//   [S,2S)   xbpre16 (GEMM1 out, hi half; conv in; dead after conv)
//   [S,3S)   fg16 (GEMM2 out, overwrites xbpre16 + x16/Win16)
//   [2S,..)  x16 (33.6MB) + Win16 (6.3MB), live only during GEMM1
//   [3S,4S)  xbc16 (conv out; dead after scan_C)
//   [4S,..)  Wg16 (9.4MB, dead after GEMM2) aliased by cA(1.5) + cS(1.5) + Wout16(3.1)
extern "C" void kernel_launch(void* const* d_in, const int* in_sizes, int n_in,
                              void* d_out, int out_size, void* d_ws, size_t ws_size,
                              hipStream_t stream) {
  const float* x    = (const float*)d_in[0];
  const float* Win  = (const float*)d_in[1];
  const float* cw   = (const float*)d_in[2];
  const float* cb   = (const float*)d_in[3];
  const float* Wg   = (const float*)d_in[4];
  const float* bg   = (const float*)d_in[5];
  const float* fb   = (const float*)d_in[6];
  const float* Wout = (const float*)d_in[7];
  float* out = (float*)d_out;
  (void)in_sizes; (void)n_in;

  const size_t S = (size_t)NT * H_M * 2;
  const size_t needed = 4 * S + (size_t)G2 * H_M * 2;
  if (ws_size < needed) {
    zero_out<<<(out_size + 255) / 256, 256, 0, stream>>>(out, out_size);
    return;
  }

  char* base = (char*)d_ws;
  unsigned short* gate16  = (unsigned short*)(base);            // becomes gh16 in-place
  unsigned short* xbpre16 = (unsigned short*)(base + S);
  unsigned short* fg16    = (unsigned short*)(base + S);        // [S,3S) after conv
  unsigned short* x16     = (unsigned short*)(base + 2 * S);    // live during GEMM1 only
  unsigned short* Win16   = (unsigned short*)(base + 2 * S + (size_t)NT * D_M * 2);
  unsigned short* xbc16   = (unsigned short*)(base + 3 * S);
  unsigned short* Wg16    = (unsigned short*)(base + 4 * S);    // dead after GEMM2
  float* cA    = (float*)(base + 4 * S);                        // aliases Wg16 (after GEMM2)
  float* cS    = cA + (size_t)N_B * NCH * H_M;
  unsigned short* Wout16  = (unsigned short*)(cS + (size_t)N_B * NCH * H_M);

  // fused bf16 conversions (x, Win, Wg)
  cvt3_bf16<<<(N4_X + N4_WIN + N4_WG + 255) / 256, 256, 0, stream>>>(
      x, x16, Win, Win16, Wg, Wg16);

  // 1) gx = x @ W_in^T, single dispatch, split output: gate16 | xbpre16
  gemm_bt8<false, true, true><<<dim3(G2 / TN, NT / TM), 512, 0, stream>>>(
      x16, Win16, gate16, xbpre16, nullptr, G2, D_M);
  // 2) depthwise causal conv -> xbc16 (2 ch/thread)
  conv_dw<<<dim3(H_M / 512, T_S, N_B), 256, 0, stream>>>(
      (const unsigned int*)xbpre16, cw, cb, (unsigned int*)xbc16);
  // 3) fg = xbc @ W_g^T + b_g  (overwrites xbpre16/x16/Win16 region)
  gemm_bt8<true, true, false><<<dim3(G2 / TN, NT / TM), 512, 0, stream>>>(
      xbc16, Wg16, fg16, nullptr, bg, G2, H_M);
  // Wout cvt into the now-dead Wg16 slot (after cA/cS)
  cvt_bf16<<<(D_M * H_M / 4 + 255) / 256, 256, 0, stream>>>(Wout, Wout16, D_M * H_M / 4);
  // 4) chunked linear scan + fused gelu(gate)*h (in-place over gate16), 2 ch/thread
  scan_A<<<dim3(H_M / 512, NCH, N_B), 256, 0, stream>>>(
      (const unsigned int*)fg16, (const unsigned int*)xbc16, fb, (float2*)cA, (float2*)cS);
  scan_C<<<dim3(H_M / 512, NCH, N_B), 256, 0, stream>>>(
      (const unsigned int*)fg16, (const unsigned int*)xbc16, fb,
      (const float2*)cA, (const float2*)cS, (unsigned int*)gate16);
  // 5) out = gh @ W_out^T  (fp32 out)
  gemm_bt8<false, false, false><<<dim3(D_M / TN, NT / TM), 512, 0, stream>>>(
      gate16, Wout16, out, nullptr, nullptr, D_M, H_M);
}

// Round 2
// 645.179 us; speedup vs baseline: 1.1280x; 1.1280x over previous
//
#include <hip/hip_runtime.h>
#include <stdint.h>
#include <math.h>

#define N_B 4
#define T_S 4096
#define D_M 1024
#define H_M 1536
#define NT  (N_B * T_S)   // 16384
#define G2  (2 * H_M)     // 3072
#define LCH 64            // timesteps per chunk
#define NCH 64            // chunks (LCH*NCH == T_S)

typedef __attribute__((ext_vector_type(8))) short short8;
typedef __attribute__((ext_vector_type(4))) float floatx4;

__device__ __forceinline__ unsigned short f2bf(float f) {
  unsigned u = __float_as_uint(f);
  u += 0x7fff + ((u >> 16) & 1);            // RNE
  return (unsigned short)(u >> 16);
}
__device__ __forceinline__ float bf2f(unsigned short u) {
  return __uint_as_float(((unsigned)u) << 16);
}
__device__ __forceinline__ float bf_lo(unsigned p) { return __uint_as_float(p << 16); }
__device__ __forceinline__ float bf_hi(unsigned p) { return __uint_as_float(p & 0xffff0000u); }
__device__ __forceinline__ unsigned bf_pack(float lo, float hi) {
  return ((unsigned)f2bf(lo)) | (((unsigned)f2bf(hi)) << 16);
}
__device__ __forceinline__ float sigmoidf_(float x) { return 1.f / (1.f + __expf(-x)); }
__device__ __forceinline__ float softplusf_(float x) {
  return (x > 20.f) ? x : log1pf(__expf(x));
}
__device__ __forceinline__ float geluf_(float x) {
  return 0.5f * x * (1.f + erff(x * 0.70710678118654752f));
}

// ---------------- zero-fill fallback (diagnostic if ws_size too small) ----------------
__global__ void zero_out(float* __restrict__ out, int n) {
  int i = blockIdx.x * 256 + threadIdx.x;
  if (i < n) out[i] = 0.f;
}

// ---------------- fused f32 -> bf16 conversion of x, Win, Wg (one launch) ----------------
#define N4_X   (NT * D_M / 4)          // 4,194,304
#define N4_WIN (G2 * D_M / 4)          //   786,432
#define N4_WG  (G2 * H_M / 4)          // 1,179,648
__global__ void cvt3_bf16(const float* __restrict__ x, unsigned short* __restrict__ x16,
                          const float* __restrict__ win, unsigned short* __restrict__ win16,
                          const float* __restrict__ wg, unsigned short* __restrict__ wg16) {
  int i = blockIdx.x * 256 + threadIdx.x;
  const float* in; unsigned short* out;
  if (i < N4_X)                { in = x;   out = x16; }
  else if (i < N4_X + N4_WIN)  { in = win; out = win16; i -= N4_X; }
  else if (i < N4_X + N4_WIN + N4_WG) { in = wg; out = wg16; i -= N4_X + N4_WIN; }
  else return;
  float4 v = ((const float4*)in)[i];
  ushort4 o;
  o.x = f2bf(v.x); o.y = f2bf(v.y); o.z = f2bf(v.z); o.w = f2bf(v.w);
  ((ushort4*)out)[i] = o;
}

__global__ void cvt_bf16(const float* __restrict__ in, unsigned short* __restrict__ out, int n4) {
  int i = blockIdx.x * 256 + threadIdx.x;
  if (i >= n4) return;
  float4 v = ((const float4*)in)[i];
  ushort4 o;
  o.x = f2bf(v.x); o.y = f2bf(v.y); o.z = f2bf(v.z); o.w = f2bf(v.w);
  ((ushort4*)out)[i] = o;
}

// ---------------- bf16 MFMA GEMM, 256x256 tile, 4-phase k-half ring schedule ----------
// C[m,n] = sum_k A[m,k]*B[n,k] (+bias[n]).  512 threads = 8 waves (2 Mx4 N), BK=64.
// LDS 64 KiB ring of 4 k-half slots: [A.kh0][A.kh1][B.kh0][B.kh1], each [256 rows x 32 k].
// Phases per tile = (khalf, nhalf), 16 MFMA each; A-frags (8) read once per khalf and
// register-held across both n-phases; B-frags (2) read per phase.
// Slot lifetimes: A.kh0 last read P1, restaged (t+1) at P2; B.kh0 last read P2, restaged P3;
// A.kh1 last read P3, restaged P4; B.kh1 last read P4, restaged next P1. Stage issues always
// come AFTER the post-MFMA barrier of the slot's last reading phase -> no write/read race.
// Counted waits (per-thread ledger, 2 loads per stage unit, 8 outstanding max):
//   P1: issue B.kh1(t); vmcnt(4) -> A.kh0(t),B.kh0(t) landed (issued 3 phases earlier)
//   P3: issue B.kh0(t+1); vmcnt(4) -> A.kh1(t),B.kh1(t) landed (2-3 phases earlier)
// Never drains in main loop; vmcnt(0) only at final tile's P3. Raw s_barrier (6/tile),
// s_setprio(1) around MFMA clusters (T5).
// Bank swizzle (fixes r1's 1.4e7 conflicts): rows are 64 B = 16 banks, so bank-group of a
// lane's ds_read_b128 = 4*(row&1) + slot. Criterion: every consecutive-8-lane group must
// cover all 8 groups. slot = kq ^ ((fr>>1)&3) gives lanes 0-7 groups {0,4,1,5,2,6,3,7} --
// a permutation (r1's kq^(fr&3) covered only 4 -> 2-way serialization). Applied via
// pre-swizzled GLOBAL source g=(tid&3)^((tid>>3)&3) (LDS dest linear, rule #21) and the
// same XOR on the read side (involution).
// XCD swizzle kept (r1: FETCH 234->141 MB): bijective since nwg%8==0 for all shapes.
#define TM 256
#define TN 256

__device__ __forceinline__ void stage16(const unsigned short* g, unsigned short* l) {
  __builtin_amdgcn_global_load_lds((__attribute__((address_space(1))) void*)g,
                                   (__attribute__((address_space(3))) void*)l, 16, 0, 0);
}

template<bool BIAS, bool OUT_BF16, bool SPLIT>
__global__ __launch_bounds__(512, 2)
void gemm_bt8(const unsigned short* __restrict__ A,
              const unsigned short* __restrict__ B,
              void* __restrict__ Cv, void* __restrict__ Cv2,
              const float* __restrict__ bias,
              int N, int K) {
  // ring slots: 0=A.kh0, 1=A.kh1, 2=B.kh0, 3=B.kh1 ; each 256x32 bf16 = 16 KB
  __shared__ __align__(16) unsigned short lds[4][8192];
  const int tid  = threadIdx.x;
  const int lane = tid & 63;
  const int wave = tid >> 6;
  const int wr = wave >> 2;                  // 0..1  (M half of tile)
  const int wc = wave & 3;                   // 0..3  (N quarter of tile)

  // bijective XCD-aware block swizzle (nwg % 8 == 0 for all shapes used)
  const int gx  = gridDim.x;
  const int nwg = gx * gridDim.y;
  const int bid = blockIdx.y * gx + blockIdx.x;
  const int cpx = nwg >> 3;
  const int swz = (bid & 7) * cpx + (bid >> 3);
  const int bm = (swz / gx) * TM;
  const int bn = (swz % gx) * TN;

  floatx4 acc[8][4];
#pragma unroll
  for (int i = 0; i < 8; i++)
#pragma unroll
    for (int j = 0; j < 4; j++)
      acc[i][j] = (floatx4){0.f, 0.f, 0.f, 0.f};

  // ---- staging: one k-half unit = 256 rows x 32 k = 1024 x 16B chunks; thread does 2.
  // chunk c = tid + 512u -> row r = c>>2 (= tid>>2 + 128u), phys slot sl = c&3.
  // logical k-group fetched: g = sl ^ ((r>>1)&3) = (tid&3) ^ ((tid>>3)&3)  (u-invariant).
  const int r0_ = tid >> 2;                  // 0..127
  const int g8  = ((tid & 3) ^ ((tid >> 3) & 3)) * 8;
  const unsigned short* Ag1 = A + (size_t)(bm + r0_)       * K + g8;
  const unsigned short* Ag2 = A + (size_t)(bm + r0_ + 128) * K + g8;
  const unsigned short* Bg1 = B + (size_t)(bn + r0_)       * K + g8;
  const unsigned short* Bg2 = B + (size_t)(bn + r0_ + 128) * K + g8;
  const int ld1 = tid * 8;                   // elem offset in slot
  const int ld2 = ld1 + 4096;

#define STAGE_A(kh, kb) do { \
    stage16(Ag1 + (kb) + (kh) * 32, &lds[kh][ld1]); \
    stage16(Ag2 + (kb) + (kh) * 32, &lds[kh][ld2]); } while (0)
#define STAGE_B(kh, kb) do { \
    stage16(Bg1 + (kb) + (kh) * 32, &lds[2 + (kh)][ld1]); \
    stage16(Bg2 + (kb) + (kh) * 32, &lds[2 + (kh)][ld2]); } while (0)

  // ---- fragment read bases: lane (fr, kq); phys slot = kq ^ ((fr>>1)&3)
  const int fr = lane & 15;
  const int kq = lane >> 4;
  const int sx = (kq ^ ((fr >> 1) & 3)) * 8;
  const int abase = (wr * 128 + fr) * 32 + sx;   // + i*512
  const int bbase = (wc * 64 + fr) * 32 + sx;    // + j*512

  const int nt = K >> 6;
  short8 af[8], bfr[2];

  // prologue: issue A.kh0(0), B.kh0(0), A.kh1(0) -- matches steady-state ledger order
  STAGE_A(0, 0); STAGE_B(0, 0); STAGE_A(1, 0);

  for (int t = 0; t < nt; ++t) {
    const int k0 = t << 6;
    const int kn = k0 + 64;
    const bool st = (t + 1 < nt);

    // ---- P1: (kh0, n01) ----
    STAGE_B(1, k0);                                  // B.kh1(t) -> slot 3
    asm volatile("s_waitcnt vmcnt(4)" ::: "memory"); // A.kh0(t), B.kh0(t) landed
    __builtin_amdgcn_s_barrier();
#pragma unroll
    for (int i = 0; i < 8; ++i) af[i]  = *(const short8*)(&lds[0][abase + i * 512]);
#pragma unroll
    for (int j = 0; j < 2; ++j) bfr[j] = *(const short8*)(&lds[2][bbase + j * 512]);
    __builtin_amdgcn_s_setprio(1);
#pragma unroll
    for (int i = 0; i < 8; ++i)
#pragma unroll
      for (int j = 0; j < 2; ++j)
        acc[i][j] = __builtin_amdgcn_mfma_f32_16x16x32_bf16(af[i], bfr[j], acc[i][j], 0, 0, 0);
    __builtin_amdgcn_s_setprio(0);
    __builtin_amdgcn_s_barrier();

    // ---- P2: (kh0, n23), A-frags reused ----
    if (st) STAGE_A(0, kn);                          // A.kh0(t+1) -> slot 0
#pragma unroll
    for (int j = 0; j < 2; ++j) bfr[j] = *(const short8*)(&lds[2][bbase + 1024 + j * 512]);
    __builtin_amdgcn_s_setprio(1);
#pragma unroll
    for (int i = 0; i < 8; ++i)
#pragma unroll
      for (int j = 0; j < 2; ++j)
        acc[i][2 + j] = __builtin_amdgcn_mfma_f32_16x16x32_bf16(af[i], bfr[j], acc[i][2 + j], 0, 0, 0);
    __builtin_amdgcn_s_setprio(0);
    __builtin_amdgcn_s_barrier();

    // ---- P3: (kh1, n01) ----
    if (st) STAGE_B(0, kn);                          // B.kh0(t+1) -> slot 2
    if (st) { asm volatile("s_waitcnt vmcnt(4)" ::: "memory"); }  // A.kh1(t), B.kh1(t)
    else    { asm volatile("s_waitcnt vmcnt(0)" ::: "memory"); }
    __builtin_amdgcn_s_barrier();
#pragma unroll
    for (int i = 0; i < 8; ++i) af[i]  = *(const short8*)(&lds[1][abase + i * 512]);
#pragma unroll
    for (int j = 0; j < 2; ++j) bfr[j] = *(const short8*)(&lds[3][bbase + j * 512]);
    __builtin_amdgcn_s_setprio(1);
#pragma unroll
    for (int i = 0; i < 8; ++i)
#pragma unroll
      for (int j = 0; j < 2; ++j)
        acc[i][j] = __builtin_amdgcn_mfma_f32_16x16x32_bf16(af[i], bfr[j], acc[i][j], 0, 0, 0);
    __builtin_amdgcn_s_setprio(0);
    __builtin_amdgcn_s_barrier();

    // ---- P4: (kh1, n23), A-frags reused ----
    if (st) STAGE_A(1, kn);                          // A.kh1(t+1) -> slot 1
#pragma unroll
    for (int j = 0; j < 2; ++j) bfr[j] = *(const short8*)(&lds[3][bbase + 1024 + j * 512]);
    __builtin_amdgcn_s_setprio(1);
#pragma unroll
    for (int i = 0; i < 8; ++i)
#pragma unroll
      for (int j = 0; j < 2; ++j)
        acc[i][2 + j] = __builtin_amdgcn_mfma_f32_16x16x32_bf16(af[i], bfr[j], acc[i][2 + j], 0, 0, 0);
    __builtin_amdgcn_s_setprio(0);
    __builtin_amdgcn_s_barrier();
  }
#undef STAGE_A
#undef STAGE_B

  // C/D layout (m89-verified): col = lane&15, row = (lane>>4)*4 + reg
  // stores ordered row-major (j innermost) so each 64B C-line's two 32B halves are
  // issued back-to-back (r1 WRITE_SIZE amplification countermeasure).
  const int half  = SPLIT ? (N >> 1) : N;
  const bool hi   = SPLIT && (bn >= half);
  void* Cb        = hi ? Cv2 : Cv;
  const int coff  = hi ? half : 0;
  const int cn = lane & 15;
  const int rb = (lane >> 4) * 4;
  float bv[4];
#pragma unroll
  for (int j = 0; j < 4; ++j)
    bv[j] = BIAS ? bias[bn + wc * 64 + j * 16 + cn] : 0.f;
  const int col0 = bn + wc * 64 + cn - coff;
#pragma unroll
  for (int i = 0; i < 8; ++i) {
    const int row0 = bm + wr * 128 + i * 16 + rb;
#pragma unroll
    for (int r = 0; r < 4; ++r) {
      const size_t rowb = (size_t)(row0 + r) * half + col0;
#pragma unroll
      for (int j = 0; j < 4; ++j) {
        float v = acc[i][j][r] + bv[j];
        if (OUT_BF16) ((unsigned short*)Cb)[rowb + j * 16] = f2bf(v);
        else          ((float*)Cb)[rowb + j * 16] = v;
      }
    }
  }
}

// ---------------- depthwise causal conv (K=4) + bias, 2 channels/thread ----------------
__global__ void conv_dw(const unsigned int* __restrict__ xbpre2, const float* __restrict__ cw,
                        const float* __restrict__ cb, unsigned int* __restrict__ xbc2) {
  int i0 = blockIdx.x * 256 + threadIdx.x;       // pair index, 0..H_M/2-1
  int t = blockIdx.y;
  size_t nt = (size_t)blockIdx.z * T_S + t;
  const int h = 2 * i0;
  const float4 wa = ((const float4*)cw)[h];      // taps for channel h
  const float4 wb = ((const float4*)cw)[h + 1];  // taps for channel h+1
  const float2 cb2 = ((const float2*)cb)[i0];
  size_t base = nt * (H_M / 2) + i0;
  unsigned p0 = xbpre2[base];
  float aa = cb2.x + wa.w * bf_lo(p0);
  float ab = cb2.y + wb.w * bf_hi(p0);
  if (t >= 1) { unsigned p = xbpre2[base - H_M / 2];
    aa += wa.z * bf_lo(p); ab += wb.z * bf_hi(p); }
  if (t >= 2) { unsigned p = xbpre2[base - 2 * (size_t)(H_M / 2)];
    aa += wa.y * bf_lo(p); ab += wb.y * bf_hi(p); }
  if (t >= 3) { unsigned p = xbpre2[base - 3 * (size_t)(H_M / 2)];
    aa += wa.x * bf_lo(p); ab += wb.x * bf_hi(p); }
  xbc2[base] = bf_pack(aa, ab);
}

// ---------------- chunked linear scan (2 channels/thread) ----------------
__global__ void scan_A(const unsigned int* __restrict__ fg2, const unsigned int* __restrict__ xbc2,
                       const float* __restrict__ fb,
                       float2* __restrict__ cA2, float2* __restrict__ cS2) {
  int i0 = blockIdx.x * 256 + threadIdx.x;       // pair index
  int ch = blockIdx.y;
  int n = blockIdx.z;
  const float2 fb2 = ((const float2*)fb)[i0];
  const float c8a = 8.f * softplusf_(fb2.x);
  const float c8b = 8.f * softplusf_(fb2.y);
  float apa = 1.f, sa = 0.f, apb = 1.f, sb = 0.f;
  size_t r = (size_t)n * T_S + (size_t)ch * LCH;
  for (int i = 0; i < LCH; i++, r++) {
    unsigned pf = fg2[r * (G2 / 2) + i0];
    unsigned pi = fg2[r * (G2 / 2) + H_M / 2 + i0];
    unsigned px = xbc2[r * (H_M / 2) + i0];
    float alpha_a = __expf(-c8a * sigmoidf_(bf_lo(pf)));
    float alpha_b = __expf(-c8b * sigmoidf_(bf_hi(pf)));
    float beta_a = sqrtf(1.f - alpha_a * alpha_a + 1e-6f);
    float beta_b = sqrtf(1.f - alpha_b * alpha_b + 1e-6f);
    sa = alpha_a * sa + beta_a * sigmoidf_(bf_lo(pi)) * bf_lo(px);
    sb = alpha_b * sb + beta_b * sigmoidf_(bf_hi(pi)) * bf_hi(px);
    apa *= alpha_a;
    apb *= alpha_b;
  }
  size_t o = ((size_t)n * NCH + ch) * (H_M / 2) + i0;
  cA2[o] = make_float2(apa, apb);
  cS2[o] = make_float2(sa, sb);
}

// phase C: per-block prescan of chunk summaries (L2-hot) computes the carry-in,
// then replay with fused gelu(gate)*h written IN-PLACE over the gate buffer.
__global__ void scan_C(const unsigned int* __restrict__ fg2, const unsigned int* __restrict__ xbc2,
                       const float* __restrict__ fb,
                       const float2* __restrict__ cA2, const float2* __restrict__ cS2,
                       unsigned int* gateh2) {
  int i0 = blockIdx.x * 256 + threadIdx.x;
  int ch = blockIdx.y;
  int n = blockIdx.z;
  const float2 fb2 = ((const float2*)fb)[i0];
  const float c8a = 8.f * softplusf_(fb2.x);
  const float c8b = 8.f * softplusf_(fb2.y);
  float sa = 0.f, sb = 0.f;
  for (int c = 0; c < ch; c++) {
    size_t o = ((size_t)n * NCH + c) * (H_M / 2) + i0;
    float2 a = cA2[o], s = cS2[o];
    sa = a.x * sa + s.x;
    sb = a.y * sb + s.y;
  }
  size_t r = (size_t)n * T_S + (size_t)ch * LCH;
  for (int i = 0; i < LCH; i++, r++) {
    unsigned pf = fg2[r * (G2 / 2) + i0];
    unsigned pi = fg2[r * (G2 / 2) + H_M / 2 + i0];
    unsigned px = xbc2[r * (H_M / 2) + i0];
    float alpha_a = __expf(-c8a * sigmoidf_(bf_lo(pf)));
    float alpha_b = __expf(-c8b * sigmoidf_(bf_hi(pf)));
    float beta_a = sqrtf(1.f - alpha_a * alpha_a + 1e-6f);
    float beta_b = sqrtf(1.f - alpha_b * alpha_b + 1e-6f);
    sa = alpha_a * sa + beta_a * sigmoidf_(bf_lo(pi)) * bf_lo(px);
    sb = alpha_b * sb + beta_b * sigmoidf_(bf_hi(pi)) * bf_hi(px);
    unsigned pg = gateh2[r * (H_M / 2) + i0];
    gateh2[r * (H_M / 2) + i0] = bf_pack(geluf_(bf_lo(pg)) * sa, geluf_(bf_hi(pg)) * sb);
  }
}

// ---------------- launcher ----------------
// Workspace layout (S = NT*H_M*2 = 50,331,648 B; peak = 4S + 9.4 MB ≈ 210.8 MB):
//   [0,S)    gate16 (GEMM1 out, lo half) -> scan_C in-place -> gh16 (GEMM3 A)
//   [S,2S)   xbpre16 (GEMM1 out, hi half; conv in; dead after conv)
//   [S,3S)   fg16 (GEMM2 out, overwrites xbpre16 + x16/Win16)
//   [2S,..)  x16 (33.6MB) + Win16 (6.3MB), live only during GEMM1
//   [3S,4S)  xbc16 (conv out; dead after scan_C)
//   [4S,..)  Wg16 (9.4MB, dead after GEMM2) aliased by cA(1.5) + cS(1.5) + Wout16(3.1)
extern "C" void kernel_launch(void* const* d_in, const int* in_sizes, int n_in,
                              void* d_out, int out_size, void* d_ws, size_t ws_size,
                              hipStream_t stream) {
  const float* x    = (const float*)d_in[0];
  const float* Win  = (const float*)d_in[1];
  const float* cw   = (const float*)d_in[2];
  const float* cb   = (const float*)d_in[3];
  const float* Wg   = (const float*)d_in[4];
  const float* bg   = (const float*)d_in[5];
  const float* fb   = (const float*)d_in[6];
  const float* Wout = (const float*)d_in[7];
  float* out = (float*)d_out;
  (void)in_sizes; (void)n_in;

  const size_t S = (size_t)NT * H_M * 2;
  const size_t needed = 4 * S + (size_t)G2 * H_M * 2;
  if (ws_size < needed) {
    zero_out<<<(out_size + 255) / 256, 256, 0, stream>>>(out, out_size);
    return;
  }

  char* base = (char*)d_ws;
  unsigned short* gate16  = (unsigned short*)(base);            // becomes gh16 in-place
  unsigned short* xbpre16 = (unsigned short*)(base + S);
  unsigned short* fg16    = (unsigned short*)(base + S);        // [S,3S) after conv
  unsigned short* x16     = (unsigned short*)(base + 2 * S);    // live during GEMM1 only
  unsigned short* Win16   = (unsigned short*)(base + 2 * S + (size_t)NT * D_M * 2);
  unsigned short* xbc16   = (unsigned short*)(base + 3 * S);
  unsigned short* Wg16    = (unsigned short*)(base + 4 * S);    // dead after GEMM2
  float* cA    = (float*)(base + 4 * S);                        // aliases Wg16 (after GEMM2)
  float* cS    = cA + (size_t)N_B * NCH * H_M;
  unsigned short* Wout16  = (unsigned short*)(cS + (size_t)N_B * NCH * H_M);

  // fused bf16 conversions (x, Win, Wg)
  cvt3_bf16<<<(N4_X + N4_WIN + N4_WG + 255) / 256, 256, 0, stream>>>(
      x, x16, Win, Win16, Wg, Wg16);

  // 1) gx = x @ W_in^T, single dispatch, split output: gate16 | xbpre16
  gemm_bt8<false, true, true><<<dim3(G2 / TN, NT / TM), 512, 0, stream>>>(
      x16, Win16, gate16, xbpre16, nullptr, G2, D_M);
  // 2) depthwise causal conv -> xbc16 (2 ch/thread)
  conv_dw<<<dim3(H_M / 512, T_S, N_B), 256, 0, stream>>>(
      (const unsigned int*)xbpre16, cw, cb, (unsigned int*)xbc16);
  // 3) fg = xbc @ W_g^T + b_g  (overwrites xbpre16/x16/Win16 region)
  gemm_bt8<true, true, false><<<dim3(G2 / TN, NT / TM), 512, 0, stream>>>(
      xbc16, Wg16, fg16, nullptr, bg, G2, H_M);
  // Wout cvt into the now-dead Wg16 slot (after cA/cS)
  cvt_bf16<<<(D_M * H_M / 4 + 255) / 256, 256, 0, stream>>>(Wout, Wout16, D_M * H_M / 4);
  // 4) chunked linear scan + fused gelu(gate)*h (in-place over gate16), 2 ch/thread
  scan_A<<<dim3(H_M / 512, NCH, N_B), 256, 0, stream>>>(
      (const unsigned int*)fg16, (const unsigned int*)xbc16, fb, (float2*)cA, (float2*)cS);
  scan_C<<<dim3(H_M / 512, NCH, N_B), 256, 0, stream>>>(
      (const unsigned int*)fg16, (const unsigned int*)xbc16, fb,
      (const float2*)cA, (const float2*)cS, (unsigned int*)gate16);
  // 5) out = gh @ W_out^T  (fp32 out)
  gemm_bt8<false, false, false><<<dim3(D_M / TN, NT / TM), 512, 0, stream>>>(
      gate16, Wout16, out, nullptr, nullptr, D_M, H_M);
}